// Round 3
// 326.652 us; speedup vs baseline: 1.0072x; 1.0072x over previous
//
#include <hip/hip_runtime.h>
#include <hip/hip_bf16.h>

#define T_ 64
#define F_ 512
#define E_ 64
#define N_ 8
#define PROJ_ELEMS ((size_t)N_ * E_ * F_ * T_)   // 16,777,216 elements
#define NSLAB ((size_t)E_ * F_ * T_)             // 2,097,152 elements per n

typedef short bf16x8 __attribute__((ext_vector_type(8)));
typedef unsigned short u16x8 __attribute__((ext_vector_type(8)));
typedef unsigned short u16x4 __attribute__((ext_vector_type(4)));
typedef float f32x4 __attribute__((ext_vector_type(4)));

static __device__ __forceinline__ f32x4 mfma_bf16(bf16x8 a, bf16x8 b, f32x4 c) {
  return __builtin_amdgcn_mfma_f32_16x16x32_bf16(a, b, c, 0, 0, 0);
}

static __device__ __forceinline__ unsigned short f2bf(float x) {
  union { float f; unsigned u; } v; v.f = x;
  unsigned r = v.u + 0x7fffu + ((v.u >> 16) & 1u);
  return (unsigned short)(r >> 16);
}
static __device__ __forceinline__ float bf2f(unsigned short s) {
  union { unsigned u; float f; } v; v.u = ((unsigned)s) << 16;
  return v.f;
}

// ROUND-2 LESSON: the inline-asm v_cvt_pk_bf16_f32 fallback produced NaNs
// (only component of the r1/r2 diff never harness-verified). Restore the
// round-0-PROVEN bit-twiddle fallback. Do not re-introduce the asm without
// an isolated correctness probe.
static __device__ __forceinline__ unsigned pack_bf16(float lo, float hi) {
#if __has_builtin(__builtin_amdgcn_cvt_pk_bf16_f32)
  typedef __bf16 bf16x2_t __attribute__((ext_vector_type(2)));
  union { bf16x2_t v; unsigned u; } c;
  c.v = __builtin_amdgcn_cvt_pk_bf16_f32(lo, hi);
  return c.u;
#else
  return ((unsigned)f2bf(lo)) | (((unsigned)f2bf(hi)) << 16);
#endif
}

// pack 8 f32 (two float4) into a bf16x8 fragment.
static __device__ __forceinline__ bf16x8 cvt2(float4 x0, float4 x1) {
  union { unsigned u[4]; bf16x8 v; } r;
  r.u[0] = pack_bf16(x0.x, x0.y);
  r.u[1] = pack_bf16(x0.z, x0.w);
  r.u[2] = pack_bf16(x1.x, x1.y);
  r.u[3] = pack_bf16(x1.z, x1.w);
  return r.v;
}

// DEVICE-side f32-vs-bf16 detection (round-1 lesson: in_sizes cannot be
// trusted for runtime dtype; harness may convert tensors to bf16 device
// buffers). bf16 weights here have |w|<2 so u16 exponent field < 0x4000;
// f32 mantissa halves exceed it w.h.p. over 64 samples.
static __device__ __forceinline__ bool detect_f32(const unsigned short* w) {
  bool m = false;
#pragma unroll
  for (int i = 0; i < 64; ++i) m |= ((unsigned)(w[i] & 0x7F80u) >= 0x4000u);
  return m;
}

// ---------------------------------------------------------------------------
// Kernel 1: projection. X[n][t][f][e] @ W[d][e]^T -> out[nb][d][f][t] (bf16)
// grid (F/4, n_count, nz). which<0: blockIdx.z selects tensor (fused path).
// v3: deep prefetch -- ALL X loads + all W loads issued into named register
// arrays before any MFMA (round-0 VGPR=52 proved only ~2 loads in flight,
// capping HBM at 2.1 TB/s by Little's law).
// ---------------------------------------------------------------------------
__global__ __launch_bounds__(256, 4) void proj_kernel(
    const void* __restrict__ Xv0, const void* __restrict__ Xv1,
    const void* __restrict__ Xv2, const void* __restrict__ Wv0,
    const void* __restrict__ Wv1, const void* __restrict__ Wv2,
    unsigned short* __restrict__ o0, unsigned short* __restrict__ o1,
    unsigned short* __restrict__ o2, int n_base, int which) {
  __shared__ unsigned short chunk[4 * 64 * 76];  // 38912 B
  const int p = (which < 0) ? (int)blockIdx.z : which;
  const void* Xv = (p == 0) ? Xv0 : ((p == 1) ? Xv1 : Xv2);
  const void* Wv = (p == 0) ? Wv0 : ((p == 1) ? Wv1 : Wv2);
  unsigned short* out = (p == 0) ? o0 : ((p == 1) ? o1 : o2);
  const int nb = blockIdx.y;
  const int na = nb + ((p == 2) ? n_base : 0);
  const int f0 = blockIdx.x * 4;
  const int tid = (int)threadIdx.x;
  const int lane = tid & 63, wv = tid >> 6;
  const int lr = lane & 15, quad = lane >> 4;
  const bool f32m = detect_f32((const unsigned short*)Wv);

  bf16x8 a0[4], a1[4];   // A[m=t][kd=e], per f
  bf16x8 wf[4][2];       // B[kd=e][n=d] = W[d][e]
  if (!f32m) {
    // X first (HBM stream, long latency, 8 loads in flight), then W (L2-hot)
#pragma unroll
    for (int f = 0; f < 4; ++f) {
      const unsigned short* xp = (const unsigned short*)Xv +
          ((size_t)((na * T_ + wv * 16 + lr) * F_ + f0 + f)) * E_ + quad * 8;
      a0[f] = *(const bf16x8*)xp;
      a1[f] = *(const bf16x8*)(xp + 32);
    }
    const unsigned short* W = (const unsigned short*)Wv;
#pragma unroll
    for (int dt = 0; dt < 4; ++dt)
#pragma unroll
      for (int h = 0; h < 2; ++h)
        wf[dt][h] = *(const bf16x8*)(W + (dt * 16 + lr) * 64 + h * 32 + quad * 8);
  } else {
    float4 xr[16];
#pragma unroll
    for (int f = 0; f < 4; ++f) {
      const float* xp = (const float*)Xv +
          ((size_t)((na * T_ + wv * 16 + lr) * F_ + f0 + f)) * E_ + quad * 8;
      xr[f * 4 + 0] = *(const float4*)xp;
      xr[f * 4 + 1] = *(const float4*)(xp + 4);
      xr[f * 4 + 2] = *(const float4*)(xp + 32);
      xr[f * 4 + 3] = *(const float4*)(xp + 36);
    }
    const float* W = (const float*)Wv;
#pragma unroll
    for (int dt = 0; dt < 4; ++dt)
#pragma unroll
      for (int h = 0; h < 2; ++h) {
        const float* wp = W + (dt * 16 + lr) * 64 + h * 32 + quad * 8;
        wf[dt][h] = cvt2(*(const float4*)wp, *(const float4*)(wp + 4));
      }
#pragma unroll
    for (int f = 0; f < 4; ++f) {
      a0[f] = cvt2(xr[f * 4 + 0], xr[f * 4 + 1]);
      a1[f] = cvt2(xr[f * 4 + 2], xr[f * 4 + 3]);
    }
  }

#pragma unroll
  for (int f = 0; f < 4; ++f) {
#pragma unroll
    for (int dt = 0; dt < 4; ++dt) {
      f32x4 acc = {0.f, 0.f, 0.f, 0.f};
      acc = mfma_bf16(a0[f], wf[dt][0], acc);
      acc = mfma_bf16(a1[f], wf[dt][1], acc);
      // C/D: col = d = lane&15, row = t = quad*4+reg
      uint2 w;
      w.x = pack_bf16(acc[0], acc[1]);
      w.y = pack_bf16(acc[2], acc[3]);
      *(uint2*)&chunk[(f * 64 + dt * 16 + lr) * 76 + wv * 16 + quad * 4] = w;
    }
  }
  __syncthreads();
  // write rows (d,f): 256 rows x 64 t; 8 parts x 16B per row
#pragma unroll
  for (int it = 0; it < 8; ++it) {
    const int slot = it * 256 + tid;
    const int row = slot >> 3;  // 0..255
    const int part = slot & 7;
    const int d = row >> 2;
    const int f = row & 3;
    uint4 v2 = *(const uint4*)&chunk[(f * 64 + d) * 76 + part * 8];
    *(uint4*)(out + ((size_t)((nb * E_ + d) * F_ + f0 + f)) * T_ + part * 8) = v2;
  }
}

// ---------------------------------------------------------------------------
// Kernel 2: attention per (n,e). grid (E, n_count), block 512 (8 waves).
// (unchanged -- byte-identical math to the round-0 passing version)
// ---------------------------------------------------------------------------
__global__ __launch_bounds__(512, 4) void attn_kernel(
    unsigned short* __restrict__ Vp,        // ws+0: V in, O out
    const unsigned short* __restrict__ Kp,  // d_out scratch: K
    const unsigned short* __restrict__ Qp, int n_base) {
  __shared__ unsigned short Vlds[T_ * 520];     // 66560 B
  __shared__ unsigned short Plds[8 * 16 * 36];  // 9216 B
  const int e = blockIdx.x, nb = blockIdx.y;
  const int na = nb + n_base;
  const size_t base = ((size_t)(na * E_ + e)) * (size_t)(F_ * T_);
  const unsigned short* Vb = Vp + base;   // [k][t]
  const unsigned short* Kb = Kp + base;   // [k][t]
  const unsigned short* Qb = Qp + ((size_t)(nb * E_ + e)) * (size_t)(F_ * T_);
  unsigned short* Ob = Vp + base;         // [q][t]
  const int tid = (int)threadIdx.x;

#pragma unroll
  for (int it = 0; it < 8; ++it) {
    int slot = it * 512 + tid;
    int t = slot & 63, kg = slot >> 6;
    u16x8 tv;
#pragma unroll
    for (int j = 0; j < 8; ++j) tv[j] = Vb[(kg * 8 + j) * 64 + t];
    *(u16x8*)&Vlds[t * 520 + kg * 8] = tv;
  }
  __syncthreads();

  const int lane = tid & 63, wv = tid >> 6;
  const int lr = lane & 15, quad = lane >> 4;
  unsigned short* Pl = Plds + wv * (16 * 36);
  const float cexp = 0.18033688011112042f;  // log2(e)/sqrt(EMBED)

#pragma unroll
  for (int iter = 0; iter < 2; ++iter) {
    const int q0 = (wv + iter * 8) * 32;
    bf16x8 qf[2][2];  // B[kd=t][n=q]
#pragma unroll
    for (int qt = 0; qt < 2; ++qt) {
      const unsigned short* qp = Qb + (q0 + qt * 16 + lr) * 64 + quad * 8;
      qf[qt][0] = *(const bf16x8*)qp;
      qf[qt][1] = *(const bf16x8*)(qp + 32);
    }
    f32x4 o[2][4];
#pragma unroll
    for (int qt = 0; qt < 2; ++qt)
#pragma unroll
      for (int tt = 0; tt < 4; ++tt) o[qt][tt] = (f32x4){0.f, 0.f, 0.f, 0.f};
    float l0 = 0.f, l1 = 0.f;

    // prefetch K chunk 0
    bf16x8 ka[2][2];
#pragma unroll
    for (int h = 0; h < 2; ++h) {
      const unsigned short* kp = Kb + (h * 16 + lr) * 64 + quad * 8;
      ka[h][0] = *(const bf16x8*)kp;
      ka[h][1] = *(const bf16x8*)(kp + 32);
    }

#pragma unroll 1
    for (int kc = 0; kc < 16; ++kc) {
      // issue next chunk's K loads first (hidden behind this chunk's compute)
      const int kc1 = (kc + 1) & 15;
      bf16x8 kn[2][2];
#pragma unroll
      for (int h = 0; h < 2; ++h) {
        const unsigned short* kp = Kb + (kc1 * 32 + h * 16 + lr) * 64 + quad * 8;
        kn[h][0] = *(const bf16x8*)kp;
        kn[h][1] = *(const bf16x8*)(kp + 32);
      }
      // S^T[k][q]
      f32x4 s[2][2];
#pragma unroll
      for (int h = 0; h < 2; ++h)
#pragma unroll
        for (int qt = 0; qt < 2; ++qt) {
          f32x4 acc = {0.f, 0.f, 0.f, 0.f};
          acc = mfma_bf16(ka[h][0], qf[qt][0], acc);
          acc = mfma_bf16(ka[h][1], qf[qt][1], acc);
          s[qt][h] = acc;
        }
      // V frags for this k-chunk (shared by both q-tiles)
      bf16x8 vfr[4];
#pragma unroll
      for (int tt = 0; tt < 4; ++tt)
        vfr[tt] = *(const bf16x8*)&Vlds[(tt * 16 + lr) * 520 + kc * 32 + quad * 8];
#pragma unroll
      for (int qt = 0; qt < 2; ++qt) {
        float lacc = 0.f;
#pragma unroll
        for (int h = 0; h < 2; ++h) {
          float p0 = __builtin_amdgcn_exp2f(s[qt][h][0] * cexp);
          float p1 = __builtin_amdgcn_exp2f(s[qt][h][1] * cexp);
          float p2 = __builtin_amdgcn_exp2f(s[qt][h][2] * cexp);
          float p3 = __builtin_amdgcn_exp2f(s[qt][h][3] * cexp);
          lacc += (p0 + p1) + (p2 + p3);
          uint2 w;
          w.x = pack_bf16(p0, p1);
          w.y = pack_bf16(p2, p3);
          *(uint2*)&Pl[lr * 36 + h * 16 + quad * 4] = w;
        }
        if (qt == 0) l0 += lacc; else l1 += lacc;
        bf16x8 pf = *(const bf16x8*)&Pl[lr * 36 + quad * 8];
#pragma unroll
        for (int tt = 0; tt < 4; ++tt)
          o[qt][tt] = mfma_bf16(vfr[tt], pf, o[qt][tt]);
      }
#pragma unroll
      for (int h = 0; h < 2; ++h) {
        ka[h][0] = kn[h][0];
        ka[h][1] = kn[h][1];
      }
    }
    l0 += __shfl_xor(l0, 16); l0 += __shfl_xor(l0, 32);
    l1 += __shfl_xor(l1, 16); l1 += __shfl_xor(l1, 32);
    const float r0 = __builtin_amdgcn_rcpf(l0);
    const float r1 = __builtin_amdgcn_rcpf(l1);
#pragma unroll
    for (int qt = 0; qt < 2; ++qt) {
      const float rv = qt ? r1 : r0;
#pragma unroll
      for (int tt = 0; tt < 4; ++tt) {
        u16x4 pk;
        pk[0] = f2bf(o[qt][tt][0] * rv);
        pk[1] = f2bf(o[qt][tt][1] * rv);
        pk[2] = f2bf(o[qt][tt][2] * rv);
        pk[3] = f2bf(o[qt][tt][3] * rv);
        *(u16x4*)(Ob + (q0 + qt * 16 + lr) * 64 + tt * 16 + quad * 4) = pk;
      }
    }
  }
}

// ---------------------------------------------------------------------------
// Kernel 3: out[n][t][q][d] = sum_e O[n][e][q][t] * Wo[d][e] + bo[d]
// v3: 64e x 4q x 64t O-tile (32 KB) staged via coalesced uint4 loads into
// LDS; B-frag gather becomes ds_read. XOR chunk swizzle ps = part ^
// (((row>>5)&3)<<1): the gather's only conflict axis is quad (rows differ
// by 32 -> bank offset = 0 mod 32); XOR gives each quad a disjoint 8-bank
// group -> conflict-free. row>>5 == ee>>3 on the read side.
// ---------------------------------------------------------------------------
__global__ __launch_bounds__(256, 4) void outproj_kernel(
    const void* __restrict__ Wov, const void* __restrict__ bov,
    const unsigned short* __restrict__ Obuf, void* __restrict__ outv) {
  __shared__ unsigned short Olds[256 * 64];  // 32768 B
  const int tid = (int)threadIdx.x;
  const int lane = tid & 63, wv = tid >> 6;
  const int lr = lane & 15, quad = lane >> 4;
  const int blk = (int)blockIdx.x;
  const int n = blk >> 7;            // 128 blocks per n
  const int q0 = (blk & 127) * 4;    // 4 q-columns per block, one per wave
  const bool f32m = detect_f32((const unsigned short*)Wov);

  // stage O[n][e][q0..q0+3][t]: 2048 x 16B coalesced loads, swizzled chunks
  const unsigned short* Ob0 = Obuf + ((size_t)(n * E_) * F_ + q0) * T_;
#pragma unroll
  for (int it = 0; it < 8; ++it) {
    const int slot = it * 256 + tid;
    const int row = slot >> 3;  // e*4 + q
    const int part = slot & 7;
    const int e = row >> 2, q = row & 3;
    const int ps = part ^ (((row >> 5) & 3) << 1);
    uint4 v = *(const uint4*)(Ob0 + ((size_t)e * F_ + q) * T_ + part * 8);
    *(uint4*)&Olds[row * 64 + ps * 8] = v;
  }

  // W frags + bias (overlap with staging loads in flight)
  bf16x8 a[4][2];
  float bias[4][4];
  if (!f32m) {
    const unsigned short* Wo = (const unsigned short*)Wov;
    const unsigned short* bo = (const unsigned short*)bov;
#pragma unroll
    for (int dt = 0; dt < 4; ++dt)
#pragma unroll
      for (int h = 0; h < 2; ++h)
        a[dt][h] = *(const bf16x8*)(Wo + (dt * 16 + lr) * 64 + h * 32 + quad * 8);
#pragma unroll
    for (int dt = 0; dt < 4; ++dt)
#pragma unroll
      for (int r = 0; r < 4; ++r)
        bias[dt][r] = bf2f(bo[dt * 16 + quad * 4 + r]);
  } else {
    const float* Wo = (const float*)Wov;
    const float* bo = (const float*)bov;
#pragma unroll
    for (int dt = 0; dt < 4; ++dt)
#pragma unroll
      for (int h = 0; h < 2; ++h) {
        const float* wp = Wo + (dt * 16 + lr) * 64 + h * 32 + quad * 8;
        a[dt][h] = cvt2(*(const float4*)wp, *(const float4*)(wp + 4));
      }
#pragma unroll
    for (int dt = 0; dt < 4; ++dt)
#pragma unroll
      for (int r = 0; r < 4; ++r)
        bias[dt][r] = bo[dt * 16 + quad * 4 + r];
  }
  __syncthreads();

  const int q = q0 + wv;
#pragma unroll
  for (int tt = 0; tt < 4; ++tt) {
    bf16x8 b[2];  // B[k=e][n=t]
#pragma unroll
    for (int h = 0; h < 2; ++h) {
      bf16x8 bv;
#pragma unroll
      for (int j = 0; j < 8; ++j) {
        const int ee = h * 32 + quad * 8 + j;
        const int row = ee * 4 + wv;
        const int cc = (tt * 2 + (lr >> 3)) ^ (((ee >> 3) & 3) << 1);
        bv[j] = (short)Olds[row * 64 + cc * 8 + (lr & 7)];
      }
      b[h] = bv;
    }
#pragma unroll
    for (int dt = 0; dt < 4; ++dt) {
      f32x4 acc = {0.f, 0.f, 0.f, 0.f};
      acc = mfma_bf16(a[dt][0], b[0], acc);
      acc = mfma_bf16(a[dt][1], b[1], acc);
      const size_t o =
          ((size_t)((n * T_ + tt * 16 + lr) * F_ + q)) * E_ + dt * 16 + quad * 4;
      if (!f32m) {
        u16x4 pk;
        pk[0] = f2bf(acc[0] + bias[dt][0]);
        pk[1] = f2bf(acc[1] + bias[dt][1]);
        pk[2] = f2bf(acc[2] + bias[dt][2]);
        pk[3] = f2bf(acc[3] + bias[dt][3]);
        *(u16x4*)((unsigned short*)outv + o) = pk;
      } else {
        float4 w;
        w.x = acc[0] + bias[dt][0];
        w.y = acc[1] + bias[dt][1];
        w.z = acc[2] + bias[dt][2];
        w.w = acc[3] + bias[dt][3];
        *(float4*)((float*)outv + o) = w;
      }
    }
  }
}

extern "C" void kernel_launch(void* const* d_in, const int* in_sizes, int n_in,
                              void* d_out, int out_size, void* d_ws, size_t ws_size,
                              hipStream_t stream) {
  (void)in_sizes; (void)n_in; (void)out_size;
  const void* value = d_in[0];
  const void* key_  = d_in[1];
  const void* query = d_in[2];
  const void* Wv    = d_in[3];
  const void* Wk    = d_in[4];
  const void* Wq    = d_in[5];
  const void* Wo    = d_in[6];
  const void* bo    = d_in[7];

  unsigned short* Vws  = (unsigned short*)d_ws;               // V proj, then O
  unsigned short* Qbuf = (unsigned short*)d_ws + PROJ_ELEMS;  // Q slab
  unsigned short* Kbuf = (unsigned short*)d_out;              // K scratch

  long spare = (long)ws_size - (long)(PROJ_ELEMS * 2);
  long qn = spare / (long)(NSLAB * 2);
  int nchunk = qn < 1 ? 1 : (qn > 8 ? 8 : (int)qn);

  if (nchunk >= 8) {
    // fast path: one fused projection dispatch, one attention dispatch
    hipLaunchKernelGGL(proj_kernel, dim3(F_ / 4, N_, 3), dim3(256), 0, stream,
                       value, key_, query, Wv, Wk, Wq, Vws, Kbuf, Qbuf, 0, -1);
    hipLaunchKernelGGL(attn_kernel, dim3(E_, N_), dim3(512), 0, stream,
                       Vws, Kbuf, Qbuf, 0);
  } else {
    hipLaunchKernelGGL(proj_kernel, dim3(F_ / 4, N_, 1), dim3(256), 0, stream,
                       value, key_, query, Wv, Wk, Wq, Vws, Kbuf, Qbuf, 0, 0);
    hipLaunchKernelGGL(proj_kernel, dim3(F_ / 4, N_, 1), dim3(256), 0, stream,
                       value, key_, query, Wv, Wk, Wq, Vws, Kbuf, Qbuf, 0, 1);
    for (int n0 = 0; n0 < N_; n0 += nchunk) {
      int c = (N_ - n0 < nchunk) ? (N_ - n0) : nchunk;
      hipLaunchKernelGGL(proj_kernel, dim3(F_ / 4, c, 1), dim3(256), 0, stream,
                         value, key_, query, Wv, Wk, Wq, Vws, Kbuf, Qbuf, n0, 2);
      hipLaunchKernelGGL(attn_kernel, dim3(E_, c), dim3(512), 0, stream,
                         Vws, Kbuf, Qbuf, n0);
    }
  }
  hipLaunchKernelGGL(outproj_kernel, dim3(1024), dim3(256), 0, stream,
                     Wo, bo, Vws, d_out);
}